// Round 2
// baseline (7184.287 us; speedup 1.0000x reference)
//
#include <hip/hip_runtime.h>

#define H 64
#define STRIDE 68   // LDS row stride in floats: 272B, 16B-aligned, breaks pow2 bank pattern

// acc[0..63] += sum_{k=0..63} src[k] * W[k*H + j]
// src: per-thread pointer (global row or LDS slot); W: wave-uniform (scalar loads)
__device__ __forceinline__ void mac64(const float* __restrict__ src,
                                      const float* __restrict__ W,
                                      float acc[H]) {
#pragma unroll 1
  for (int k0 = 0; k0 < 64; k0 += 4) {
    const float v0 = src[k0 + 0], v1 = src[k0 + 1], v2 = src[k0 + 2], v3 = src[k0 + 3];
    const float* w0 = W + (size_t)(k0 + 0) * H;
    const float* w1 = W + (size_t)(k0 + 1) * H;
    const float* w2 = W + (size_t)(k0 + 2) * H;
    const float* w3 = W + (size_t)(k0 + 3) * H;
#pragma unroll
    for (int j = 0; j < H; ++j) {
      float a = acc[j];
      a = fmaf(v0, w0[j], a);
      a = fmaf(v1, w1[j], a);
      a = fmaf(v2, w2[j], a);
      a = fmaf(v3, w3[j], a);
      acc[j] = a;
    }
  }
}

__device__ __forceinline__ void mac64_scaled(const float* __restrict__ src, float s,
                                             const float* __restrict__ W,
                                             float acc[H]) {
#pragma unroll 1
  for (int k0 = 0; k0 < 64; k0 += 4) {
    const float v0 = src[k0 + 0] * s, v1 = src[k0 + 1] * s, v2 = src[k0 + 2] * s, v3 = src[k0 + 3] * s;
    const float* w0 = W + (size_t)(k0 + 0) * H;
    const float* w1 = W + (size_t)(k0 + 1) * H;
    const float* w2 = W + (size_t)(k0 + 2) * H;
    const float* w3 = W + (size_t)(k0 + 3) * H;
#pragma unroll
    for (int j = 0; j < H; ++j) {
      float a = acc[j];
      a = fmaf(v0, w0[j], a);
      a = fmaf(v1, w1[j], a);
      a = fmaf(v2, w2[j], a);
      a = fmaf(v3, w3[j], a);
      acc[j] = a;
    }
  }
}

__global__ void __launch_bounds__(128) k_deg(int E_, const int* __restrict__ col,
                                             float* __restrict__ denom) {
  int e = blockIdx.x * 128 + threadIdx.x;
  if (e < E_) atomicAdd(&denom[col[e]], 1.0f);
}

__global__ void __launch_bounds__(128) k_inv(int N_, float* __restrict__ denom) {
  int n = blockIdx.x * 128 + threadIdx.x;
  if (n < N_) denom[n] = 1.0f / fmaxf(denom[n], 1.0f);
}

// Per edge: new_ea = MLP2([x_r; x_c; ea]); m = MLP2([x_r; new_ea]); agg[col] += m
__global__ void __launch_bounds__(128) k_edge(
    int E_, const float* __restrict__ x,
    const int* __restrict__ row, const int* __restrict__ col,
    const float* __restrict__ ea_in, float* __restrict__ ea_out,
    const float* __restrict__ eW1, const float* __restrict__ eb1,
    const float* __restrict__ eW2, const float* __restrict__ eb2,
    const float* __restrict__ n1W1, const float* __restrict__ n1b1,
    const float* __restrict__ n1W2, const float* __restrict__ n1b2,
    float* __restrict__ agg) {
  __shared__ float lds[128 * STRIDE];
  float* slot = lds + (size_t)threadIdx.x * STRIDE;
  int e = blockIdx.x * 128 + threadIdx.x;
  if (e >= E_) return;
  const int r = row[e], c = col[e];
  const float* xr = x + (size_t)r * H;
  const float* xc = x + (size_t)c * H;

  float acc[H];
  // edge MLP, layer 1: h = relu([xr;xc;ea] @ W1 + b1)
#pragma unroll
  for (int j = 0; j < H; ++j) acc[j] = eb1[j];
  mac64(xr, eW1, acc);
  mac64(xc, eW1 + (size_t)64 * H, acc);
  mac64(ea_in + (size_t)e * H, eW1 + (size_t)128 * H, acc);
#pragma unroll
  for (int j = 0; j < H; ++j) slot[j] = fmaxf(acc[j], 0.f);

  // edge MLP, layer 2: o = h @ W2 + b2
#pragma unroll
  for (int j = 0; j < H; ++j) acc[j] = eb2[j];
  mac64(slot, eW2, acc);

  // write new edge_attr (in-place safe: own row fully read above)
  {
    float4* eo = (float4*)(ea_out + (size_t)e * H);
#pragma unroll
    for (int t = 0; t < 16; ++t)
      eo[t] = make_float4(acc[4 * t], acc[4 * t + 1], acc[4 * t + 2], acc[4 * t + 3]);
  }
  // stash o for node-MLP1 input
#pragma unroll
  for (int j = 0; j < H; ++j) slot[j] = acc[j];

  // node MLP1, layer 1: h2 = relu([xr; o] @ W1 + b1)
#pragma unroll
  for (int j = 0; j < H; ++j) acc[j] = n1b1[j];
  mac64(xr, n1W1, acc);
  mac64(slot, n1W1 + (size_t)64 * H, acc);
#pragma unroll
  for (int j = 0; j < H; ++j) slot[j] = fmaxf(acc[j], 0.f);

  // node MLP1, layer 2: m = h2 @ W2 + b2
#pragma unroll
  for (int j = 0; j < H; ++j) acc[j] = n1b2[j];
  mac64(slot, n1W2, acc);

  float* ag = agg + (size_t)c * H;
#pragma unroll
  for (int j = 0; j < H; ++j) atomicAdd(ag + j, acc[j]);
}

// Per node: x_new = MLP2([x; agg/denom])
__global__ void __launch_bounds__(128) k_node(
    int N_, const float* __restrict__ x_in, float* __restrict__ x_out,
    const float* __restrict__ agg, const float* __restrict__ invd,
    const float* __restrict__ W1, const float* __restrict__ b1,
    const float* __restrict__ W2, const float* __restrict__ b2) {
  __shared__ float lds[128 * STRIDE];
  float* slot = lds + (size_t)threadIdx.x * STRIDE;
  int n = blockIdx.x * 128 + threadIdx.x;
  if (n >= N_) return;
  const float inv = invd[n];
  const float* xn = x_in + (size_t)n * H;
  const float* an = agg + (size_t)n * H;

  float acc[H];
#pragma unroll
  for (int j = 0; j < H; ++j) acc[j] = b1[j];
  mac64(xn, W1, acc);
  mac64_scaled(an, inv, W1 + (size_t)64 * H, acc);
#pragma unroll
  for (int j = 0; j < H; ++j) slot[j] = fmaxf(acc[j], 0.f);

#pragma unroll
  for (int j = 0; j < H; ++j) acc[j] = b2[j];
  mac64(slot, W2, acc);

  float4* xo = (float4*)(x_out + (size_t)n * H);
#pragma unroll
  for (int t = 0; t < 16; ++t)
    xo[t] = make_float4(acc[4 * t], acc[4 * t + 1], acc[4 * t + 2], acc[4 * t + 3]);
}

extern "C" void kernel_launch(void* const* d_in, const int* in_sizes, int n_in,
                              void* d_out, int out_size, void* d_ws, size_t ws_size,
                              hipStream_t stream) {
  const float* x0   = (const float*)d_in[0];
  const int*   ei   = (const int*)d_in[1];
  const float* ea0  = (const float*)d_in[2];
  const float* eW1  = (const float*)d_in[3];
  const float* eb1  = (const float*)d_in[4];
  const float* eW2  = (const float*)d_in[5];
  const float* eb2  = (const float*)d_in[6];
  const float* n1W1 = (const float*)d_in[7];
  const float* n1b1 = (const float*)d_in[8];
  const float* n1W2 = (const float*)d_in[9];
  const float* n1b2 = (const float*)d_in[10];
  const float* n2W1 = (const float*)d_in[11];
  const float* n2b1 = (const float*)d_in[12];
  const float* n2W2 = (const float*)d_in[13];
  const float* n2b2 = (const float*)d_in[14];

  const int Nn = in_sizes[0] / H;
  const int Ee = in_sizes[2] / H;
  const int Ll = in_sizes[4] / H;   // eb1 is [L, H]

  const int* row = ei;
  const int* col = ei + Ee;

  float* x_out  = (float*)d_out;                      // [N, H]
  float* ea_out = (float*)d_out + (size_t)Nn * H;     // [E, H]
  float* agg    = (float*)d_ws;                       // [N, H]
  float* denom  = agg + (size_t)Nn * H;               // [N] (counts -> 1/max(cnt,1))

  hipMemsetAsync(denom, 0, (size_t)Nn * sizeof(float), stream);
  k_deg<<<(Ee + 127) / 128, 128, 0, stream>>>(Ee, col, denom);
  k_inv<<<(Nn + 127) / 128, 128, 0, stream>>>(Nn, denom);

  const float* xin  = x0;
  const float* eain = ea0;
  for (int l = 0; l < Ll; ++l) {
    hipMemsetAsync(agg, 0, (size_t)Nn * H * sizeof(float), stream);
    k_edge<<<(Ee + 127) / 128, 128, 0, stream>>>(
        Ee, xin, row, col, eain, ea_out,
        eW1 + (size_t)l * 3 * H * H, eb1 + (size_t)l * H,
        eW2 + (size_t)l * H * H,     eb2 + (size_t)l * H,
        n1W1 + (size_t)l * 2 * H * H, n1b1 + (size_t)l * H,
        n1W2 + (size_t)l * H * H,     n1b2 + (size_t)l * H,
        agg);
    k_node<<<(Nn + 127) / 128, 128, 0, stream>>>(
        Nn, xin, x_out, agg, denom,
        n2W1 + (size_t)l * 2 * H * H, n2b1 + (size_t)l * H,
        n2W2 + (size_t)l * H * H,     n2b2 + (size_t)l * H);
    xin = x_out;
    eain = ea_out;
  }
}

// Round 5
// 1137.103 us; speedup vs baseline: 6.3181x; 6.3181x over previous
//
#include <hip/hip_runtime.h>

// Fused MPNN block on MFMA (gfx950). H=64.
// Per 64-row tile: chain of GEMMs A[64xK] x W[Kx64] using mfma_f32_16x16x32_bf16.
// All operands split-bf16 (hi+lo), 3 MFMA passes per product -> ~fp32 accuracy.
// LDS tiles XOR-swizzled (byte ^= (row&7)<<4) -> conflict-free ds_read_b128 frags.

#define H 64

typedef __attribute__((ext_vector_type(8))) short short8v;
typedef __attribute__((ext_vector_type(4))) float f32x4;
typedef unsigned short u16;
typedef unsigned int u32;

__device__ __forceinline__ u16 f2bf(float x) {
  u32 u = __float_as_uint(x);
  u32 r = (u + 0x7FFFu + ((u >> 16) & 1u)) >> 16;   // RNE
  return (u16)r;
}
__device__ __forceinline__ float bf2f(u16 h) {
  return __uint_as_float(((u32)h) << 16);
}
__device__ __forceinline__ void split2(float x, u16& hi, u16& lo) {
  hi = f2bf(x);
  lo = f2bf(x - bf2f(hi));
}
__device__ __forceinline__ int swz(int row, int colbyte) {
  return row * 128 + (colbyte ^ ((row & 7) << 4));
}

// Stage a [64 rows x 64 cols] f32 tile into hi/lo bf16 LDS (swizzled).
// MODE 0: rows rowbase+row (clamped). MODE 1: rows gidx[rowbase+row]. MODE 2: direct + per-row scale.
template <int MODE>
__device__ __forceinline__ void stageA(const float* __restrict__ src,
                                       const int* __restrict__ gidx,
                                       int rowbase, int rowmax,
                                       const float* __restrict__ scale,
                                       u16* __restrict__ hi, u16* __restrict__ lo,
                                       int tid) {
#pragma unroll
  for (int it = 0; it < 2; ++it) {
    int row = it * 32 + (tid >> 4);
    int e = rowbase + row;
    if (e > rowmax) e = rowmax;
    int g = (MODE == 1) ? gidx[e] : e;
    int c0 = (tid & 15) * 4;
    float4 v = *(const float4*)(src + (size_t)g * H + c0);
    if (MODE == 2) { float s = scale[g]; v.x *= s; v.y *= s; v.z *= s; v.w *= s; }
    u16 h0, l0, h1, l1, h2, l2, h3, l3;
    split2(v.x, h0, l0); split2(v.y, h1, l1); split2(v.z, h2, l2); split2(v.w, h3, l3);
    int b = swz(row, c0 * 2);
    *(uint2*)((char*)hi + b) = make_uint2((u32)h0 | ((u32)h1 << 16), (u32)h2 | ((u32)h3 << 16));
    *(uint2*)((char*)lo + b) = make_uint2((u32)l0 | ((u32)l1 << 16), (u32)l2 | ((u32)l3 << 16));
  }
}

// Stage a [64 n x 64 k] slice of a pre-split transposed weight (layout [64 n][K k]) into LDS.
__device__ __forceinline__ void stageB(const u16* __restrict__ sh, const u16* __restrict__ sl,
                                       int K, int k0,
                                       u16* __restrict__ bh, u16* __restrict__ bl, int tid) {
  int row = tid >> 3;
  int s = tid & 7;
  int b = row * 128 + ((s * 16) ^ ((row & 7) << 4));
  uint4 vh = *(const uint4*)(sh + (size_t)row * K + k0 + s * 8);
  uint4 vl = *(const uint4*)(sl + (size_t)row * K + k0 + s * 8);
  *(uint4*)((char*)bh + b) = vh;
  *(uint4*)((char*)bl + b) = vl;
}

// One K=64 segment: acc[2] += A_tile x B_tile (3-pass split-bf16).
// A frag: row = lane&15, k = (lane>>4)*8+i ; B frag: col = lane&15, same k.
__device__ __forceinline__ void mm_seg(const u16* __restrict__ Ah, const u16* __restrict__ Al,
                                       const u16* __restrict__ Bh, const u16* __restrict__ Bl,
                                       int lane, int rowblk, int cpair, f32x4* acc) {
  const int arow = rowblk * 16 + (lane & 15);
  const int koff = (lane >> 4) * 16;  // bytes
#pragma unroll
  for (int ks = 0; ks < 2; ++ks) {
    const int kb = ks * 64 + koff;
    short8v ah = *(const short8v*)((const char*)Ah + swz(arow, kb));
    short8v al = *(const short8v*)((const char*)Al + swz(arow, kb));
#pragma unroll
    for (int t = 0; t < 2; ++t) {
      int brow = (cpair * 2 + t) * 16 + (lane & 15);
      short8v bh = *(const short8v*)((const char*)Bh + swz(brow, kb));
      short8v bl = *(const short8v*)((const char*)Bl + swz(brow, kb));
      acc[t] = __builtin_amdgcn_mfma_f32_16x16x32_bf16(ah, bh, acc[t], 0, 0, 0);
      acc[t] = __builtin_amdgcn_mfma_f32_16x16x32_bf16(ah, bl, acc[t], 0, 0, 0);
      acc[t] = __builtin_amdgcn_mfma_f32_16x16x32_bf16(al, bh, acc[t], 0, 0, 0);
    }
  }
}

// acc -> bias(+ReLU) -> split-bf16 into an H-buffer (swizzled).
// C frag: col = lane&15, row = (lane>>4)*4 + reg (m89-verified).
template <bool RELU>
__device__ __forceinline__ void epi_toH(const f32x4* acc, int lane, int rowblk, int cpair,
                                        const float* __restrict__ bias,
                                        u16* __restrict__ hh, u16* __restrict__ hl) {
#pragma unroll
  for (int t = 0; t < 2; ++t) {
    int col = (cpair * 2 + t) * 16 + (lane & 15);
    float bb = bias[col];
#pragma unroll
    for (int r = 0; r < 4; ++r) {
      int row = rowblk * 16 + (lane >> 4) * 4 + r;
      float v = acc[t][r] + bb;
      if (RELU) v = fmaxf(v, 0.f);
      u16 h, l;
      split2(v, h, l);
      int byte = swz(row, col * 2);
      *(u16*)((char*)hh + byte) = h;
      *(u16*)((char*)hl + byte) = l;
    }
  }
}

// Split+transpose weights: in [L][K][64] f32 -> out hi/lo [L][64][K] bf16.
__global__ void __launch_bounds__(256) k_prep(const float* __restrict__ W,
                                              u16* __restrict__ hi, u16* __restrict__ lo,
                                              int K, int total) {
  int idx = blockIdx.x * 256 + threadIdx.x;
  if (idx >= total) return;
  int per = K * 64;
  int l = idx / per;
  int rem = idx - l * per;
  int k = rem >> 6, n = rem & 63;
  float v = W[idx];
  u16 h, lw;
  split2(v, h, lw);
  size_t o = (size_t)l * per + (size_t)n * K + k;
  hi[o] = h;
  lo[o] = lw;
}

__global__ void __launch_bounds__(256) k_deg(int E_, const int* __restrict__ col,
                                             float* __restrict__ denom) {
  int e = blockIdx.x * 256 + threadIdx.x;
  if (e < E_) atomicAdd(&denom[col[e]], 1.0f);
}
__global__ void __launch_bounds__(256) k_inv(int N_, float* __restrict__ denom) {
  int n = blockIdx.x * 256 + threadIdx.x;
  if (n < N_) denom[n] = 1.0f / fmaxf(denom[n], 1.0f);
}

// Per 64-edge tile: ea' = MLP2([xr|xc|ea]); m = MLP2([xr|ea']); agg[col] += m.
__global__ void __launch_bounds__(512, 4) k_edge(
    int E_, const float* __restrict__ x,
    const int* __restrict__ rowg, const int* __restrict__ colg,
    const float* __restrict__ ea_in, float* __restrict__ ea_out,
    const u16* __restrict__ eW1h, const u16* __restrict__ eW1l, const float* __restrict__ eb1,
    const u16* __restrict__ eW2h, const u16* __restrict__ eW2l, const float* __restrict__ eb2,
    const u16* __restrict__ n1W1h, const u16* __restrict__ n1W1l, const float* __restrict__ n1b1,
    const u16* __restrict__ n1W2h, const u16* __restrict__ n1W2l, const float* __restrict__ n1b2,
    float* __restrict__ agg) {
  __shared__ u16 Ah[4096], Al[4096], Bh[4096], Bl[4096];
  __shared__ u16 H1h[4096], H1l[4096], H2h[4096], H2l[4096];
  const int tid = threadIdx.x;
  const int lane = tid & 63, wave = tid >> 6;
  const int rowblk = wave & 3, cpair = wave >> 2;
  const int e0 = blockIdx.x * 64;
  const int emax = E_ - 1;

  // GEMM1: h = relu([xr|xc|ea] @ eW1 + eb1), K=192 in 3 segments
  f32x4 acc1[2] = {{0.f, 0.f, 0.f, 0.f}, {0.f, 0.f, 0.f, 0.f}};
  stageA<1>(x, rowg, e0, emax, nullptr, Ah, Al, tid);
  stageB(eW1h, eW1l, 192, 0, Bh, Bl, tid);
  __syncthreads();
  mm_seg(Ah, Al, Bh, Bl, lane, rowblk, cpair, acc1);
  __syncthreads();
  stageA<1>(x, colg, e0, emax, nullptr, Ah, Al, tid);
  stageB(eW1h, eW1l, 192, 64, Bh, Bl, tid);
  __syncthreads();
  mm_seg(Ah, Al, Bh, Bl, lane, rowblk, cpair, acc1);
  __syncthreads();
  stageA<0>(ea_in, nullptr, e0, emax, nullptr, Ah, Al, tid);
  stageB(eW1h, eW1l, 192, 128, Bh, Bl, tid);
  __syncthreads();
  mm_seg(Ah, Al, Bh, Bl, lane, rowblk, cpair, acc1);
  __syncthreads();

  epi_toH<true>(acc1, lane, rowblk, cpair, eb1, H1h, H1l);
  stageB(eW2h, eW2l, 64, 0, Bh, Bl, tid);
  __syncthreads();

  // GEMM2: o = h @ eW2 + eb2
  f32x4 acc2[2] = {{0.f, 0.f, 0.f, 0.f}, {0.f, 0.f, 0.f, 0.f}};
  mm_seg(H1h, H1l, Bh, Bl, lane, rowblk, cpair, acc2);
  __syncthreads();

  // o epilogue: write ea_out (f32, coalesced per 16-lane group) + H2 (bf16 hi/lo)
#pragma unroll
  for (int t = 0; t < 2; ++t) {
    int col = (cpair * 2 + t) * 16 + (lane & 15);
    float bb = eb2[col];
#pragma unroll
    for (int r = 0; r < 4; ++r) {
      int rr = rowblk * 16 + (lane >> 4) * 4 + r;
      float v = acc2[t][r] + bb;
      int e = e0 + rr;
      if (e < E_) ea_out[(size_t)e * H + col] = v;
      u16 h, l;
      split2(v, h, l);
      int byte = swz(rr, col * 2);
      *(u16*)((char*)H2h + byte) = h;
      *(u16*)((char*)H2l + byte) = l;
    }
  }
  stageA<1>(x, rowg, e0, emax, nullptr, Ah, Al, tid);
  stageB(n1W1h, n1W1l, 128, 0, Bh, Bl, tid);
  __syncthreads();

  // GEMM3: h2 = relu([xr|o] @ n1W1 + n1b1), K=128 in 2 segments
  f32x4 acc3[2] = {{0.f, 0.f, 0.f, 0.f}, {0.f, 0.f, 0.f, 0.f}};
  mm_seg(Ah, Al, Bh, Bl, lane, rowblk, cpair, acc3);
  __syncthreads();
  stageB(n1W1h, n1W1l, 128, 64, Bh, Bl, tid);
  __syncthreads();
  mm_seg(H2h, H2l, Bh, Bl, lane, rowblk, cpair, acc3);
  __syncthreads();

  epi_toH<true>(acc3, lane, rowblk, cpair, n1b1, H1h, H1l);
  stageB(n1W2h, n1W2l, 64, 0, Bh, Bl, tid);
  __syncthreads();

  // GEMM4: m = h2 @ n1W2 + n1b2 -> scatter-add (64B-contiguous per 16-lane group)
  f32x4 acc4[2] = {{0.f, 0.f, 0.f, 0.f}, {0.f, 0.f, 0.f, 0.f}};
  mm_seg(H1h, H1l, Bh, Bl, lane, rowblk, cpair, acc4);
#pragma unroll
  for (int t = 0; t < 2; ++t) {
    int col = (cpair * 2 + t) * 16 + (lane & 15);
    float bb = n1b2[col];
#pragma unroll
    for (int r = 0; r < 4; ++r) {
      int rr = rowblk * 16 + (lane >> 4) * 4 + r;
      int e = e0 + rr;
      if (e < E_) {
        int c = colg[e];
        atomicAdd(agg + (size_t)c * H + col, acc4[t][r] + bb);
      }
    }
  }
}

// Per 64-node tile: x' = MLP2([x | agg*inv])
__global__ void __launch_bounds__(512, 4) k_node(
    int N_, const float* __restrict__ x_in, float* __restrict__ x_out,
    const float* __restrict__ agg, const float* __restrict__ inv,
    const u16* __restrict__ W1h, const u16* __restrict__ W1l, const float* __restrict__ b1,
    const u16* __restrict__ W2h, const u16* __restrict__ W2l, const float* __restrict__ b2) {
  __shared__ u16 Ah[4096], Al[4096], Bh[4096], Bl[4096], H1h[4096], H1l[4096];
  const int tid = threadIdx.x;
  const int lane = tid & 63, wave = tid >> 6;
  const int rowblk = wave & 3, cpair = wave >> 2;
  const int n0 = blockIdx.x * 64;
  const int nmax = N_ - 1;

  f32x4 acc1[2] = {{0.f, 0.f, 0.f, 0.f}, {0.f, 0.f, 0.f, 0.f}};
  stageA<0>(x_in, nullptr, n0, nmax, nullptr, Ah, Al, tid);
  stageB(W1h, W1l, 128, 0, Bh, Bl, tid);
  __syncthreads();
  mm_seg(Ah, Al, Bh, Bl, lane, rowblk, cpair, acc1);
  __syncthreads();
  stageA<2>(agg, nullptr, n0, nmax, inv, Ah, Al, tid);
  stageB(W1h, W1l, 128, 64, Bh, Bl, tid);
  __syncthreads();
  mm_seg(Ah, Al, Bh, Bl, lane, rowblk, cpair, acc1);
  __syncthreads();

  epi_toH<true>(acc1, lane, rowblk, cpair, b1, H1h, H1l);
  stageB(W2h, W2l, 64, 0, Bh, Bl, tid);
  __syncthreads();

  f32x4 acc2[2] = {{0.f, 0.f, 0.f, 0.f}, {0.f, 0.f, 0.f, 0.f}};
  mm_seg(H1h, H1l, Bh, Bl, lane, rowblk, cpair, acc2);
#pragma unroll
  for (int t = 0; t < 2; ++t) {
    int col = (cpair * 2 + t) * 16 + (lane & 15);
    float bb = b2[col];
#pragma unroll
    for (int r = 0; r < 4; ++r) {
      int rr = rowblk * 16 + (lane >> 4) * 4 + r;
      int n = n0 + rr;
      if (n < N_) x_out[(size_t)n * H + col] = acc2[t][r] + bb;
    }
  }
}

extern "C" void kernel_launch(void* const* d_in, const int* in_sizes, int n_in,
                              void* d_out, int out_size, void* d_ws, size_t ws_size,
                              hipStream_t stream) {
  const float* x0   = (const float*)d_in[0];
  const int*   ei   = (const int*)d_in[1];
  const float* ea0  = (const float*)d_in[2];
  const float* eW1  = (const float*)d_in[3];
  const float* eb1  = (const float*)d_in[4];
  const float* eW2  = (const float*)d_in[5];
  const float* eb2  = (const float*)d_in[6];
  const float* n1W1 = (const float*)d_in[7];
  const float* n1b1 = (const float*)d_in[8];
  const float* n1W2 = (const float*)d_in[9];
  const float* n1b2 = (const float*)d_in[10];
  const float* n2W1 = (const float*)d_in[11];
  const float* n2b1 = (const float*)d_in[12];
  const float* n2W2 = (const float*)d_in[13];
  const float* n2b2 = (const float*)d_in[14];

  const int Nn = in_sizes[0] / H;
  const int Ee = in_sizes[2] / H;
  const int Ll = in_sizes[4] / H;  // eb1 is [L, H]

  const int* row = ei;
  const int* col = ei + Ee;

  float* x_out  = (float*)d_out;                   // [N, H]
  float* ea_out = (float*)d_out + (size_t)Nn * H;  // [E, H]

  float* agg   = (float*)d_ws;                     // [N, H]
  float* denom = agg + (size_t)Nn * H;             // [N]
  size_t off = ((size_t)Nn * H + Nn) * sizeof(float);
  off = (off + 255) & ~(size_t)255;
  u16* wb = (u16*)((char*)d_ws + off);

  // pre-split transposed weights, per layer tile sizes (u16 elements)
  const size_t sW1e = 64 * 192, sW2 = 64 * 64, sW1n = 64 * 128;
  u16* eW1h  = wb;                     u16* eW1l  = eW1h  + (size_t)Ll * sW1e;
  u16* eW2h  = eW1l  + (size_t)Ll * sW1e; u16* eW2l  = eW2h  + (size_t)Ll * sW2;
  u16* n1W1h = eW2l  + (size_t)Ll * sW2;  u16* n1W1l = n1W1h + (size_t)Ll * sW1n;
  u16* n1W2h = n1W1l + (size_t)Ll * sW1n; u16* n1W2l = n1W2h + (size_t)Ll * sW2;
  u16* n2W1h = n1W2l + (size_t)Ll * sW2;  u16* n2W1l = n2W1h + (size_t)Ll * sW1n;
  u16* n2W2h = n2W1l + (size_t)Ll * sW1n; u16* n2W2l = n2W2h + (size_t)Ll * sW2;

  auto prep = [&](const float* W, u16* hi, u16* lo, int K) {
    int total = Ll * K * 64;
    k_prep<<<(total + 255) / 256, 256, 0, stream>>>(W, hi, lo, K, total);
  };
  prep(eW1, eW1h, eW1l, 192);
  prep(eW2, eW2h, eW2l, 64);
  prep(n1W1, n1W1h, n1W1l, 128);
  prep(n1W2, n1W2h, n1W2l, 64);
  prep(n2W1, n2W1h, n2W1l, 128);
  prep(n2W2, n2W2h, n2W2l, 64);

  hipMemsetAsync(denom, 0, (size_t)Nn * sizeof(float), stream);
  k_deg<<<(Ee + 255) / 256, 256, 0, stream>>>(Ee, col, denom);
  k_inv<<<(Nn + 255) / 256, 256, 0, stream>>>(Nn, denom);

  const float* xin  = x0;
  const float* eain = ea0;
  const int egrid = (Ee + 63) / 64;
  const int ngrid = (Nn + 63) / 64;
  for (int l = 0; l < Ll; ++l) {
    hipMemsetAsync(agg, 0, (size_t)Nn * H * sizeof(float), stream);
    k_edge<<<egrid, 512, 0, stream>>>(
        Ee, xin, row, col, eain, ea_out,
        eW1h + (size_t)l * sW1e, eW1l + (size_t)l * sW1e, eb1 + (size_t)l * H,
        eW2h + (size_t)l * sW2,  eW2l + (size_t)l * sW2,  eb2 + (size_t)l * H,
        n1W1h + (size_t)l * sW1n, n1W1l + (size_t)l * sW1n, n1b1 + (size_t)l * H,
        n1W2h + (size_t)l * sW2,  n1W2l + (size_t)l * sW2,  n1b2 + (size_t)l * H,
        agg);
    k_node<<<ngrid, 512, 0, stream>>>(
        Nn, xin, x_out, agg, denom,
        n2W1h + (size_t)l * sW1n, n2W1l + (size_t)l * sW1n, n2b1 + (size_t)l * H,
        n2W2h + (size_t)l * sW2,  n2W2l + (size_t)l * sW2,  n2b2 + (size_t)l * H);
    xin = x_out;
    eain = ea_out;
  }
}